// Round 3
// baseline (150.338 us; speedup 1.0000x reference)
//
#include <hip/hip_runtime.h>

// Lorenz96 RK4, fp32 — coalesced + ILP:
//   10 lanes per row x 1 float4 per lane; 6 rows per 60-lane tile.
//   Each wave now processes G=4 consecutive tiles (240 float4 = 24 rows):
//   4 independent loads in flight, 4 independent RK4 chains interleaved
//   stage-by-stage, 4 stores. Halos via __shfl within the 10-lane row
//   group (same neighbor lanes for every tile). No LDS, no barriers.

#define FORCE 8.0f
#define G 4

__global__ __launch_bounds__(256)
void lorenz96_rk4_ilp(const float4* __restrict__ x0,
                      const float* __restrict__ dt_p,
                      float4* __restrict__ out,
                      long nf4)   // batch * 10 float4s total
{
    const long tid  = (long)blockIdx.x * blockDim.x + threadIdx.x;
    const long wave = tid >> 6;
    const int  lane = (int)(tid & 63);
    const int  lrow = lane / 10;          // row within tile, 0..5 (6 = idle)
    const int  c    = lane - lrow * 10;   // float4 column within row, 0..9
    const bool laneok = (lane < 60);

    const int lL = lrow * 10 + (c == 0 ? 9 : c - 1);
    const int lR = lrow * 10 + (c == 9 ? 0 : c + 1);

    const float dt  = dt_p[0];
    const float hdt = 0.5f * dt;
    const float s6  = dt * (1.0f / 6.0f);

    const long base = wave * (60L * G) + lane;

    bool  act[G];
    float x0r[G], x1r[G], x2r[G], x3r[G];   // input state
    float a0[G], a1[G], a2[G], a3[G];       // k1+2k2+2k3+k4 accumulator
    float y0[G], y1[G], y2[G], y3[G];       // stage state

    // --- 4 independent coalesced loads, issued back-to-back ---
    #pragma unroll
    for (int t = 0; t < G; ++t) {
        const long f = base + 60L * t;
        act[t] = laneok && (f < nf4);
        float4 v = make_float4(0.f, 0.f, 0.f, 0.f);
        if (act[t]) v = x0[f];
        x0r[t] = v.x; x1r[t] = v.y; x2r[t] = v.z; x3r[t] = v.w;
    }

    // derivative of (s0..s3) for tile t; halo via shfl in the row group
    auto deriv = [&](float s0, float s1, float s2, float s3,
                     float& d0, float& d1, float& d2, float& d3) {
        float hL2 = __shfl(s2, lL);
        float hL3 = __shfl(s3, lL);
        float hR0 = __shfl(s0, lR);
        d0 = (s1  - hL2) * hL3 - s0 + FORCE;
        d1 = (s2  - hL3) * s0  - s1 + FORCE;
        d2 = (s3  - s0 ) * s1  - s2 + FORCE;
        d3 = (hR0 - s1 ) * s2  - s3 + FORCE;
    };

    // --- stage 1: k1 = f(x); y = x + hdt*k1 ---  (tiles independent)
    #pragma unroll
    for (int t = 0; t < G; ++t) {
        float k0, k1, k2, k3;
        deriv(x0r[t], x1r[t], x2r[t], x3r[t], k0, k1, k2, k3);
        a0[t] = k0; a1[t] = k1; a2[t] = k2; a3[t] = k3;
        y0[t] = x0r[t] + hdt * k0; y1[t] = x1r[t] + hdt * k1;
        y2[t] = x2r[t] + hdt * k2; y3[t] = x3r[t] + hdt * k3;
    }
    // --- stage 2: k2 = f(y); y = x + hdt*k2 ---
    #pragma unroll
    for (int t = 0; t < G; ++t) {
        float k0, k1, k2, k3;
        deriv(y0[t], y1[t], y2[t], y3[t], k0, k1, k2, k3);
        a0[t] += 2.0f * k0; a1[t] += 2.0f * k1;
        a2[t] += 2.0f * k2; a3[t] += 2.0f * k3;
        y0[t] = x0r[t] + hdt * k0; y1[t] = x1r[t] + hdt * k1;
        y2[t] = x2r[t] + hdt * k2; y3[t] = x3r[t] + hdt * k3;
    }
    // --- stage 3: k3 = f(y); y = x + dt*k3 ---
    #pragma unroll
    for (int t = 0; t < G; ++t) {
        float k0, k1, k2, k3;
        deriv(y0[t], y1[t], y2[t], y3[t], k0, k1, k2, k3);
        a0[t] += 2.0f * k0; a1[t] += 2.0f * k1;
        a2[t] += 2.0f * k2; a3[t] += 2.0f * k3;
        y0[t] = x0r[t] + dt * k0; y1[t] = x1r[t] + dt * k1;
        y2[t] = x2r[t] + dt * k2; y3[t] = x3r[t] + dt * k3;
    }
    // --- stage 4: k4 = f(y); acc += k4 ---
    #pragma unroll
    for (int t = 0; t < G; ++t) {
        float k0, k1, k2, k3;
        deriv(y0[t], y1[t], y2[t], y3[t], k0, k1, k2, k3);
        a0[t] += k0; a1[t] += k1; a2[t] += k2; a3[t] += k3;
    }

    // --- 4 independent coalesced stores ---
    #pragma unroll
    for (int t = 0; t < G; ++t) {
        const long f = base + 60L * t;
        if (act[t]) {
            float4 r;
            r.x = x0r[t] + s6 * a0[t];
            r.y = x1r[t] + s6 * a1[t];
            r.z = x2r[t] + s6 * a2[t];
            r.w = x3r[t] + s6 * a3[t];
            out[f] = r;
        }
    }
}

extern "C" void kernel_launch(void* const* d_in, const int* in_sizes, int n_in,
                              void* d_out, int out_size, void* d_ws, size_t ws_size,
                              hipStream_t stream) {
    const float4* x0 = (const float4*)d_in[0];
    // d_in[1] = t (unused; autonomous system)
    const float* dt = (const float*)d_in[2];
    float4* out = (float4*)d_out;

    const long nf4 = (long)in_sizes[0] / 4;             // batch*10 float4s
    const long nwaves = (nf4 + 60L * G - 1) / (60L * G); // 240 f4 per wave
    const int block = 256;                               // 4 waves/block
    const long grid = (nwaves + 3) / 4;
    lorenz96_rk4_ilp<<<dim3((unsigned)grid), dim3(block), 0, stream>>>(x0, dt, out, nf4);
}

// Round 4
// 148.836 us; speedup vs baseline: 1.0101x; 1.0101x over previous
//
#include <hip/hip_runtime.h>

// Lorenz96 RK4, fp32 — fully-aligned streaming layout:
//   block = 320 threads = 32 complete rows (320 float4 = 5 KiB contiguous).
//   One float4 per thread; every wave's load/store is a dense, 1 KiB-aligned
//   64-lane burst (no split cache lines between waves/XCDs, no idle lanes).
//   Row-wrap stencil halos (left f4's .z/.w, right f4's .x) are exchanged
//   through a 7.5 KB LDS publish (3 floats/thread), double-buffered so each
//   RK4 stage costs exactly one __syncthreads (4 total).
//
//   dxdt[i] = (x[i+1] - x[i-2]) * x[i-1] - x[i] + 8; classic RK4, t unused.

#define FORCE 8.0f

__global__ __launch_bounds__(320)
void lorenz96_rk4_blk(const float4* __restrict__ x0,
                      const float* __restrict__ dt_p,
                      float4* __restrict__ out,
                      long nf4)
{
    const int  t = threadIdx.x;                    // 0..319
    const long g = (long)blockIdx.x * 320 + t;     // global float4 index
    const bool act = (g < nf4);

    const int e  = t % 10;                         // f4 position within row
    const int tl = (e == 0) ? t + 9 : t - 1;       // left f4 (row wrap)
    const int tr = (e == 9) ? t - 9 : t + 1;       // right f4 (row wrap)

    // double-buffered halo publish: s0, s2, s3 of each thread's f4
    __shared__ float pA0[320], pA2[320], pA3[320];
    __shared__ float pB0[320], pB2[320], pB3[320];

    const float dt  = dt_p[0];
    const float hdt = 0.5f * dt;
    const float s6  = dt * (1.0f / 6.0f);

    float4 v = make_float4(0.f, 0.f, 0.f, 0.f);
    if (act) v = x0[g];
    const float x0r = v.x, x1r = v.y, x2r = v.z, x3r = v.w;

    float y0, y1, y2, y3;      // stage state
    float a0, a1, a2, a3;      // k1 + 2k2 + 2k3 + k4
    float k0, k1, k2, k3;
    float hL2, hL3, hR0;

    // ---- stage 1: k1 = f(x) ----
    pA0[t] = x0r; pA2[t] = x2r; pA3[t] = x3r;
    __syncthreads();
    hL2 = pA2[tl]; hL3 = pA3[tl]; hR0 = pA0[tr];
    k0 = (x1r - hL2) * hL3 - x0r + FORCE;
    k1 = (x2r - hL3) * x0r - x1r + FORCE;
    k2 = (x3r - x0r) * x1r - x2r + FORCE;
    k3 = (hR0 - x1r) * x2r - x3r + FORCE;
    a0 = k0; a1 = k1; a2 = k2; a3 = k3;
    y0 = x0r + hdt * k0; y1 = x1r + hdt * k1;
    y2 = x2r + hdt * k2; y3 = x3r + hdt * k3;

    // ---- stage 2: k2 = f(y) ----
    pB0[t] = y0; pB2[t] = y2; pB3[t] = y3;
    __syncthreads();
    hL2 = pB2[tl]; hL3 = pB3[tl]; hR0 = pB0[tr];
    k0 = (y1 - hL2) * hL3 - y0 + FORCE;
    k1 = (y2 - hL3) * y0 - y1 + FORCE;
    k2 = (y3 - y0) * y1 - y2 + FORCE;
    k3 = (hR0 - y1) * y2 - y3 + FORCE;
    a0 += 2.0f * k0; a1 += 2.0f * k1; a2 += 2.0f * k2; a3 += 2.0f * k3;
    y0 = x0r + hdt * k0; y1 = x1r + hdt * k1;
    y2 = x2r + hdt * k2; y3 = x3r + hdt * k3;

    // ---- stage 3: k3 = f(y) ----
    pA0[t] = y0; pA2[t] = y2; pA3[t] = y3;
    __syncthreads();
    hL2 = pA2[tl]; hL3 = pA3[tl]; hR0 = pA0[tr];
    k0 = (y1 - hL2) * hL3 - y0 + FORCE;
    k1 = (y2 - hL3) * y0 - y1 + FORCE;
    k2 = (y3 - y0) * y1 - y2 + FORCE;
    k3 = (hR0 - y1) * y2 - y3 + FORCE;
    a0 += 2.0f * k0; a1 += 2.0f * k1; a2 += 2.0f * k2; a3 += 2.0f * k3;
    y0 = x0r + dt * k0; y1 = x1r + dt * k1;
    y2 = x2r + dt * k2; y3 = x3r + dt * k3;

    // ---- stage 4: k4 = f(y) ----
    pB0[t] = y0; pB2[t] = y2; pB3[t] = y3;
    __syncthreads();
    hL2 = pB2[tl]; hL3 = pB3[tl]; hR0 = pB0[tr];
    k0 = (y1 - hL2) * hL3 - y0 + FORCE;
    k1 = (y2 - hL3) * y0 - y1 + FORCE;
    k2 = (y3 - y0) * y1 - y2 + FORCE;
    k3 = (hR0 - y1) * y2 - y3 + FORCE;
    a0 += k0; a1 += k1; a2 += k2; a3 += k3;

    if (act) {
        float4 r;
        r.x = x0r + s6 * a0;
        r.y = x1r + s6 * a1;
        r.z = x2r + s6 * a2;
        r.w = x3r + s6 * a3;
        out[g] = r;
    }
}

extern "C" void kernel_launch(void* const* d_in, const int* in_sizes, int n_in,
                              void* d_out, int out_size, void* d_ws, size_t ws_size,
                              hipStream_t stream) {
    const float4* x0 = (const float4*)d_in[0];
    // d_in[1] = t (unused; autonomous system)
    const float* dt = (const float*)d_in[2];
    float4* out = (float4*)d_out;

    const long nf4 = (long)in_sizes[0] / 4;        // batch*10 = 5,242,880
    const long grid = (nf4 + 319) / 320;           // 16384 blocks, exact
    lorenz96_rk4_blk<<<dim3((unsigned)grid), dim3(320), 0, stream>>>(x0, dt, out, nf4);
}